// Round 11
// baseline (823.788 us; speedup 1.0000x reference)
//
#include <hip/hip_runtime.h>

#define EMB 64
#define NBINS 64

// ---------- Kernel A: segment boundaries (segment_ids sorted) ----------
__global__ void seg_bounds_kernel(const int* __restrict__ seg,
                                  int* __restrict__ row_start,
                                  int T, int B) {
    int t = blockIdx.x * blockDim.x + threadIdx.x;
    if (t >= T) return;
    int s  = seg[t];
    int sp = (t == 0) ? -1 : seg[t - 1];
    for (int b = sp + 1; b <= s; ++b) row_start[b] = t;
    if (t == T - 1) {
        for (int b = s + 1; b <= B; ++b) row_start[b] = T;
    }
}

// ---------- Kernel CQ+H (fused): q4 conversion  |  length histogram ----------
// Blocks [0, cvtBlocks): quantize implicit_factors rows to int4 + scale.
// Blocks [cvtBlocks, ...): histogram of row lengths into hist[NBINS].
__global__ __launch_bounds__(256) void cvt_and_hist_kernel(
    const float* __restrict__ src, uint* __restrict__ dst,
    float* __restrict__ scales, int nrows, int cvtBlocks,
    const int* __restrict__ row_start, int* __restrict__ hist, int B) {
    if ((int)blockIdx.x < cvtBlocks) {
        const int wave = (int)((blockIdx.x * blockDim.x + threadIdx.x) >> 6);
        const int lane = threadIdx.x & 63;
        const int g = lane >> 3, sub = lane & 7;
        const int r = wave * 8 + g;
        if (r >= nrows) return;

        const float* p = src + (size_t)r * EMB + (sub << 3);
        float e[8];
        #pragma unroll
        for (int k = 0; k < 8; ++k) e[k] = p[k];
        float mx = 0.f;
        #pragma unroll
        for (int k = 0; k < 8; ++k) mx = fmaxf(mx, fabsf(e[k]));
        mx = fmaxf(mx, __shfl_xor(mx, 1, 64));
        mx = fmaxf(mx, __shfl_xor(mx, 2, 64));
        mx = fmaxf(mx, __shfl_xor(mx, 4, 64));

        const float scale = mx * (1.0f / 7.5f);
        const float inv   = (mx > 0.f) ? (7.5f / mx) : 0.f;

        uint w = 0;
        #pragma unroll
        for (int k = 0; k < 8; ++k) {
            int q = (int)rintf(fmaf(e[k], inv, 7.5f));
            q = q < 0 ? 0 : (q > 15 ? 15 : q);
            w |= ((uint)q) << (4 * k);
        }
        dst[(size_t)r * 8 + sub] = w;
        if (sub == 0) scales[r] = scale;
    } else {
        __shared__ int lh[NBINS];
        if (threadIdx.x < NBINS) lh[threadIdx.x] = 0;
        __syncthreads();
        const int hb = (int)blockIdx.x - cvtBlocks;
        const int nHistBlocks = (int)gridDim.x - cvtBlocks;
        const int stride = nHistBlocks * (int)blockDim.x;
        for (int b = hb * (int)blockDim.x + (int)threadIdx.x; b < B; b += stride) {
            int n = row_start[b + 1] - row_start[b];
            n = n > (NBINS - 1) ? (NBINS - 1) : n;
            atomicAdd(&lh[n], 1);
        }
        __syncthreads();
        if (threadIdx.x < NBINS && lh[threadIdx.x] > 0)
            atomicAdd(&hist[threadIdx.x], lh[threadIdx.x]);
    }
}

// ---------- Kernel S2: prefix-sum bins, zero cursors (1 block) ----------
__global__ void bin_prefix_kernel(const int* __restrict__ hist,
                                  int* __restrict__ bin_base,
                                  int* __restrict__ bin_cursor) {
    if (threadIdx.x == 0) {
        int acc = 0;
        for (int i = 0; i < NBINS; ++i) { bin_base[i] = acc; acc += hist[i]; }
    }
    if (threadIdx.x < NBINS) bin_cursor[threadIdx.x] = 0;
}

// ---------- Kernel S3: scatter rows into length-sorted order ----------
__global__ __launch_bounds__(256) void make_order_kernel(
    const int* __restrict__ row_start, const int* __restrict__ bin_base,
    int* __restrict__ bin_cursor, int* __restrict__ ord, int B) {
    const int stride = (int)gridDim.x * (int)blockDim.x;
    for (int b = (int)(blockIdx.x * blockDim.x + threadIdx.x); b < B; b += stride) {
        int n = row_start[b + 1] - row_start[b];
        n = n > (NBINS - 1) ? (NBINS - 1) : n;
        const int pos = atomicAdd(&bin_cursor[n], 1);
        ord[bin_base[n] + pos] = b;
    }
}

// ---------- Kernel B v8: 8 equal-length rows per wave, q4 gather ----------
__device__ __forceinline__ float qdot8(uint u, const float4 a, const float4 b) {
    const uint lo = u & 0x0F0F0F0Fu;
    const uint hi = (u >> 4) & 0x0F0F0F0Fu;
    const float e0 = (float)(lo & 0xffu),         e1 = (float)(hi & 0xffu);
    const float e2 = (float)((lo >> 8) & 0xffu),  e3 = (float)((hi >> 8) & 0xffu);
    const float e4 = (float)((lo >> 16) & 0xffu), e5 = (float)((hi >> 16) & 0xffu);
    const float e6 = (float)(lo >> 24),           e7 = (float)(hi >> 24);
    return e0*a.x + e1*a.y + e2*a.z + e3*a.w
         + e4*b.x + e5*b.y + e6*b.z + e7*b.w;
}

__global__ __launch_bounds__(256) void svdpp_main_q4(
    const int*   __restrict__ scientist_ids,
    const int*   __restrict__ paper_ids,
    const int*   __restrict__ flat_papers,
    const int*   __restrict__ row_start,
    const int*   __restrict__ ord,
    const float* __restrict__ scientist_factors,
    const float* __restrict__ paper_factors,
    const uint*  __restrict__ imp_q4,
    const float* __restrict__ imp_scale,
    const float* __restrict__ scientist_bias,
    const float* __restrict__ paper_bias,
    float*       __restrict__ out,
    int B) {
    const int wave = (int)((blockIdx.x * blockDim.x + threadIdx.x) >> 6);
    const int lane = threadIdx.x & 63;
    const int g    = lane >> 3;        // group -> row slot
    const int sub  = lane & 7;         // dims [8*sub, 8*sub+7]
    const int idx  = wave * 8 + g;
    if (idx >= B) return;
    const int b = ord[idx];            // length-equalized schedule

    const int sid   = __builtin_nontemporal_load(scientist_ids + b);
    const int pid   = __builtin_nontemporal_load(paper_ids + b);
    const int start = row_start[b];
    const int end   = row_start[b + 1];

    // paper row (hot 25.6MB table): plain cached float4 loads
    const float4* pf = reinterpret_cast<const float4*>(
        paper_factors + ((size_t)pid << 6)) + 2 * sub;
    const float4 pe0 = pf[0];
    const float4 pe1 = pf[1];
    const float pesum = pe0.x + pe0.y + pe0.z + pe0.w
                      + pe1.x + pe1.y + pe1.z + pe1.w;

    // scientist row (zero-reuse 256MB table): scalar nt loads
    const float* sf = scientist_factors + ((size_t)sid << 6) + (sub << 3);
    float se[8];
    #pragma unroll
    for (int k = 0; k < 8; ++k) se[k] = __builtin_nontemporal_load(sf + k);

    const float sb = __builtin_nontemporal_load(scientist_bias + sid);
    const float pb = __builtin_nontemporal_load(paper_bias + pid);

    const float base = se[0]*pe0.x + se[1]*pe0.y + se[2]*pe0.z + se[3]*pe0.w
                     + se[4]*pe1.x + se[5]*pe1.y + se[6]*pe1.z + se[7]*pe1.w;

    // gather loop: 4 independent chains; all groups have (near-)equal n.
    float A0 = 0.f, A1 = 0.f, A2 = 0.f, A3 = 0.f;
    float S0 = 0.f, S1 = 0.f, S2 = 0.f, S3 = 0.f;
    int e = start;
    for (; e + 4 <= end; e += 4) {
        const int p0 = flat_papers[e];
        const int p1 = flat_papers[e + 1];
        const int p2 = flat_papers[e + 2];
        const int p3 = flat_papers[e + 3];
        const uint u0 = imp_q4[((size_t)p0 << 3) + sub];
        const uint u1 = imp_q4[((size_t)p1 << 3) + sub];
        const uint u2 = imp_q4[((size_t)p2 << 3) + sub];
        const uint u3 = imp_q4[((size_t)p3 << 3) + sub];
        const float s0 = imp_scale[p0];
        const float s1 = imp_scale[p1];
        const float s2 = imp_scale[p2];
        const float s3 = imp_scale[p3];
        A0 = fmaf(s0, qdot8(u0, pe0, pe1), A0);  S0 += s0;
        A1 = fmaf(s1, qdot8(u1, pe0, pe1), A1);  S1 += s1;
        A2 = fmaf(s2, qdot8(u2, pe0, pe1), A2);  S2 += s2;
        A3 = fmaf(s3, qdot8(u3, pe0, pe1), A3);  S3 += s3;
    }
    for (; e < end; ++e) {
        const int p = flat_papers[e];
        const uint u = imp_q4[((size_t)p << 3) + sub];
        const float s = imp_scale[p];
        A0 = fmaf(s, qdot8(u, pe0, pe1), A0);  S0 += s;
    }
    const float acc = ((A0 + A1) + (A2 + A3))
                    - 7.5f * ((S0 + S1) + (S2 + S3)) * pesum;

    const int n = end - start;
    const float scale = (n > 0) ? rsqrtf((float)n) : 0.0f;
    float v = base + scale * acc;

    // reduce within the 8-lane group (lane bits 0..2)
    v += __shfl_xor(v, 1, 64);
    v += __shfl_xor(v, 2, 64);
    v += __shfl_xor(v, 4, 64);

    if (sub == 0) {
        __builtin_nontemporal_store(v + sb + pb + 3.82f, out + b);
    }
}

// ---------- f32 fallback (ws too small) ----------
__global__ __launch_bounds__(256) void svdpp_main_f32(
    const int*   __restrict__ scientist_ids,
    const int*   __restrict__ paper_ids,
    const int*   __restrict__ flat_papers,
    const int*   __restrict__ row_start,
    const float* __restrict__ scientist_factors,
    const float* __restrict__ paper_factors,
    const float* __restrict__ implicit_factors,
    const float* __restrict__ scientist_bias,
    const float* __restrict__ paper_bias,
    float*       __restrict__ out,
    int B) {
    const int wave = (int)((blockIdx.x * blockDim.x + threadIdx.x) >> 6);
    const int lane = threadIdx.x & 63;
    if (wave >= B) return;
    const int b   = wave;
    const int g   = lane >> 4;
    const int sub = lane & 15;

    const int start = row_start[b];
    const int end   = row_start[b + 1];
    const int n     = end - start;

    float4 accA = make_float4(0.f,0.f,0.f,0.f);
    int i = start;
    for (; i < end; i += 4) {
        const int e = i + g;
        if (e < end) {
            const int p = flat_papers[e];
            const float4 r = *reinterpret_cast<const float4*>(
                implicit_factors + ((size_t)p << 6) + (sub << 2));
            accA.x += r.x; accA.y += r.y; accA.z += r.z; accA.w += r.w;
        }
    }

    const float scale = (n > 0) ? rsqrtf((float)n) : 0.0f;
    const int sid = scientist_ids[b];
    const int pid = paper_ids[b];
    const float4 se = *reinterpret_cast<const float4*>(
        scientist_factors + ((size_t)sid << 6) + (sub << 2));
    const float4 pe = *reinterpret_cast<const float4*>(
        paper_factors + ((size_t)pid << 6) + (sub << 2));

    const float basedot = se.x*pe.x + se.y*pe.y + se.z*pe.z + se.w*pe.w;
    const float tdot    = accA.x*pe.x + accA.y*pe.y + accA.z*pe.z + accA.w*pe.w;
    float v = scale * tdot + ((g == 0) ? basedot : 0.0f);

    #pragma unroll
    for (int off = 1; off < 64; off <<= 1) v += __shfl_xor(v, off, 64);

    if (lane == 0) {
        out[b] = v + scientist_bias[sid] + paper_bias[pid] + 3.82f;
    }
}

extern "C" void kernel_launch(void* const* d_in, const int* in_sizes, int n_in,
                              void* d_out, int out_size, void* d_ws, size_t ws_size,
                              hipStream_t stream) {
    const int* scientist_ids       = (const int*)d_in[0];
    const int* paper_ids           = (const int*)d_in[1];
    const int* flat_papers         = (const int*)d_in[2];
    const int* segment_ids         = (const int*)d_in[3];
    const float* scientist_factors = (const float*)d_in[4];
    const float* paper_factors     = (const float*)d_in[5];
    const float* implicit_factors  = (const float*)d_in[6];
    const float* scientist_bias    = (const float*)d_in[7];
    const float* paper_bias        = (const float*)d_in[8];
    float* out = (float*)d_out;

    const int B      = in_sizes[0];
    const int T      = in_sizes[2];
    const int IMP_N  = in_sizes[6];          // NUM_PAPERS * EMB
    const int NROWS  = IMP_N / EMB;          // NUM_PAPERS

    auto align64 = [](size_t x) { return (x + 63) & ~(size_t)63; };
    size_t off0 = 0;                                   // row_start (B+1 ints)
    size_t off1 = align64(off0 + (size_t)(B + 1) * 4); // imp_q4  (NROWS*32B)
    size_t off2 = align64(off1 + (size_t)NROWS * 32);  // imp_scale (NROWS*4B)
    size_t off3 = align64(off2 + (size_t)NROWS * 4);   // ord (B ints)
    size_t off4 = align64(off3 + (size_t)B * 4);       // hist/base/cursor
    const size_t need = off4 + 3 * NBINS * 4;

    int*   row_start  = (int*)((char*)d_ws + off0);
    uint*  imp_q4     = (uint*)((char*)d_ws + off1);
    float* imp_scale  = (float*)((char*)d_ws + off2);
    int*   ord        = (int*)((char*)d_ws + off3);
    int*   hist       = (int*)((char*)d_ws + off4);
    int*   bin_base   = hist + NBINS;
    int*   bin_cursor = hist + 2 * NBINS;

    {
        const int threads = 256;
        const int blocks  = (T + threads - 1) / threads;
        seg_bounds_kernel<<<blocks, threads, 0, stream>>>(segment_ids, row_start, T, B);
    }

    if (ws_size >= need) {
        hipMemsetAsync(hist, 0, NBINS * 4, stream);
        {
            const int threads   = 256;
            const int cvtBlocks = (NROWS + 31) / 32;   // 8 rows per wave
            const int histBlocks = 256;
            cvt_and_hist_kernel<<<cvtBlocks + histBlocks, threads, 0, stream>>>(
                implicit_factors, imp_q4, imp_scale, NROWS, cvtBlocks,
                row_start, hist, B);
        }
        bin_prefix_kernel<<<1, 64, 0, stream>>>(hist, bin_base, bin_cursor);
        {
            const int threads = 256;
            make_order_kernel<<<256, threads, 0, stream>>>(
                row_start, bin_base, bin_cursor, ord, B);
        }
        {
            const int threads = 256;                   // 32 rows per block
            const int blocks  = (B + 31) / 32;
            svdpp_main_q4<<<blocks, threads, 0, stream>>>(
                scientist_ids, paper_ids, flat_papers, row_start, ord,
                scientist_factors, paper_factors, imp_q4, imp_scale,
                scientist_bias, paper_bias, out, B);
        }
    } else {
        const int threads = 256;
        const int blocks  = (B + 3) / 4;
        svdpp_main_f32<<<blocks, threads, 0, stream>>>(
            scientist_ids, paper_ids, flat_papers, row_start,
            scientist_factors, paper_factors, implicit_factors,
            scientist_bias, paper_bias, out, B);
    }
}

// Round 12
// 139.451 us; speedup vs baseline: 5.9074x; 5.9074x over previous
//
#include <hip/hip_runtime.h>

#define EMB 64
#define NBINS 64

// ---------- Kernel A: segment boundaries (segment_ids sorted) ----------
__global__ void seg_bounds_kernel(const int* __restrict__ seg,
                                  int* __restrict__ row_start,
                                  int T, int B) {
    int t = blockIdx.x * blockDim.x + threadIdx.x;
    if (t >= T) return;
    int s  = seg[t];
    int sp = (t == 0) ? -1 : seg[t - 1];
    for (int b = sp + 1; b <= s; ++b) row_start[b] = t;
    if (t == T - 1) {
        for (int b = s + 1; b <= B; ++b) row_start[b] = T;
    }
}

// ---------- Kernel CQ+H (fused): q4 conversion | length histogram ----------
__global__ __launch_bounds__(256) void cvt_and_hist_kernel(
    const float* __restrict__ src, uint* __restrict__ dst,
    float* __restrict__ scales, int nrows, int cvtBlocks,
    const int* __restrict__ row_start, int* __restrict__ hist, int B) {
    if ((int)blockIdx.x < cvtBlocks) {
        const int wave = (int)((blockIdx.x * blockDim.x + threadIdx.x) >> 6);
        const int lane = threadIdx.x & 63;
        const int g = lane >> 3, sub = lane & 7;
        const int r = wave * 8 + g;
        if (r >= nrows) return;

        const float* p = src + (size_t)r * EMB + (sub << 3);
        float e[8];
        #pragma unroll
        for (int k = 0; k < 8; ++k) e[k] = p[k];
        float mx = 0.f;
        #pragma unroll
        for (int k = 0; k < 8; ++k) mx = fmaxf(mx, fabsf(e[k]));
        mx = fmaxf(mx, __shfl_xor(mx, 1, 64));
        mx = fmaxf(mx, __shfl_xor(mx, 2, 64));
        mx = fmaxf(mx, __shfl_xor(mx, 4, 64));

        const float scale = mx * (1.0f / 7.5f);
        const float inv   = (mx > 0.f) ? (7.5f / mx) : 0.f;

        uint w = 0;
        #pragma unroll
        for (int k = 0; k < 8; ++k) {
            int q = (int)rintf(fmaf(e[k], inv, 7.5f));
            q = q < 0 ? 0 : (q > 15 ? 15 : q);
            w |= ((uint)q) << (4 * k);
        }
        dst[(size_t)r * 8 + sub] = w;
        if (sub == 0) scales[r] = scale;
    } else {
        __shared__ int lh[NBINS];
        if (threadIdx.x < NBINS) lh[threadIdx.x] = 0;
        __syncthreads();
        const int hb = (int)blockIdx.x - cvtBlocks;
        const int nHistBlocks = (int)gridDim.x - cvtBlocks;
        const int stride = nHistBlocks * (int)blockDim.x;
        for (int b = hb * (int)blockDim.x + (int)threadIdx.x; b < B; b += stride) {
            int n = row_start[b + 1] - row_start[b];
            n = n > (NBINS - 1) ? (NBINS - 1) : n;
            atomicAdd(&lh[n], 1);
        }
        __syncthreads();
        if (threadIdx.x < NBINS && lh[threadIdx.x] > 0)
            atomicAdd(&hist[threadIdx.x], lh[threadIdx.x]);
    }
}

// ---------- Kernel S2: prefix-sum bins -> global cursors (1 block) ----------
__global__ void bin_prefix_kernel(const int* __restrict__ hist,
                                  int* __restrict__ bin_cursor) {
    if (threadIdx.x == 0) {
        int acc = 0;
        for (int i = 0; i < NBINS; ++i) { bin_cursor[i] = acc; acc += hist[i]; }
    }
}

// ---------- Kernel S3 v2: block-local counting-sort scatter ----------
// Each block owns a contiguous row chunk. LDS histogram -> ONE global
// atomicAdd per (block,bin) to reserve a range -> LDS-cursor scatter.
// Global atomics: 256*64=16K spread over 64 lines (vs 262K on 64 words).
__global__ __launch_bounds__(256) void make_order_kernel(
    const int* __restrict__ row_start, int* __restrict__ bin_cursor,
    int* __restrict__ ord, int B) {
    __shared__ int lh[NBINS];
    __shared__ int lbase[NBINS];
    const int tid = (int)threadIdx.x;
    const int chunk = (B + (int)gridDim.x - 1) / (int)gridDim.x;
    const int b0 = (int)blockIdx.x * chunk;
    const int b1 = min(b0 + chunk, B);

    if (tid < NBINS) lh[tid] = 0;
    __syncthreads();
    for (int b = b0 + tid; b < b1; b += (int)blockDim.x) {
        int n = row_start[b + 1] - row_start[b];
        n = n > (NBINS - 1) ? (NBINS - 1) : n;
        atomicAdd(&lh[n], 1);
    }
    __syncthreads();
    if (tid < NBINS) {
        const int c = lh[tid];
        lbase[tid] = (c > 0) ? atomicAdd(&bin_cursor[tid], c) : 0;
        lh[tid] = 0;
    }
    __syncthreads();
    for (int b = b0 + tid; b < b1; b += (int)blockDim.x) {
        int n = row_start[b + 1] - row_start[b];
        n = n > (NBINS - 1) ? (NBINS - 1) : n;
        const int off = atomicAdd(&lh[n], 1);
        ord[lbase[n] + off] = b;
    }
}

// ---------- Kernel B v8: 8 equal-length rows per wave, q4 gather ----------
__device__ __forceinline__ float qdot8(uint u, const float4 a, const float4 b) {
    const uint lo = u & 0x0F0F0F0Fu;
    const uint hi = (u >> 4) & 0x0F0F0F0Fu;
    const float e0 = (float)(lo & 0xffu),         e1 = (float)(hi & 0xffu);
    const float e2 = (float)((lo >> 8) & 0xffu),  e3 = (float)((hi >> 8) & 0xffu);
    const float e4 = (float)((lo >> 16) & 0xffu), e5 = (float)((hi >> 16) & 0xffu);
    const float e6 = (float)(lo >> 24),           e7 = (float)(hi >> 24);
    return e0*a.x + e1*a.y + e2*a.z + e3*a.w
         + e4*b.x + e5*b.y + e6*b.z + e7*b.w;
}

__global__ __launch_bounds__(256) void svdpp_main_q4(
    const int*   __restrict__ scientist_ids,
    const int*   __restrict__ paper_ids,
    const int*   __restrict__ flat_papers,
    const int*   __restrict__ row_start,
    const int*   __restrict__ ord,
    const float* __restrict__ scientist_factors,
    const float* __restrict__ paper_factors,
    const uint*  __restrict__ imp_q4,
    const float* __restrict__ imp_scale,
    const float* __restrict__ scientist_bias,
    const float* __restrict__ paper_bias,
    float*       __restrict__ out,
    int B) {
    const int wave = (int)((blockIdx.x * blockDim.x + threadIdx.x) >> 6);
    const int lane = threadIdx.x & 63;
    const int g    = lane >> 3;        // group -> row slot
    const int sub  = lane & 7;         // dims [8*sub, 8*sub+7]
    const int idx  = wave * 8 + g;
    if (idx >= B) return;
    const int b = ord[idx];            // length-equalized schedule

    const int sid   = __builtin_nontemporal_load(scientist_ids + b);
    const int pid   = __builtin_nontemporal_load(paper_ids + b);
    const int start = row_start[b];
    const int end   = row_start[b + 1];

    // paper row (hot 25.6MB table): plain cached float4 loads
    const float4* pf = reinterpret_cast<const float4*>(
        paper_factors + ((size_t)pid << 6)) + 2 * sub;
    const float4 pe0 = pf[0];
    const float4 pe1 = pf[1];
    const float pesum = pe0.x + pe0.y + pe0.z + pe0.w
                      + pe1.x + pe1.y + pe1.z + pe1.w;

    // scientist row (zero-reuse 256MB table): scalar nt loads
    const float* sf = scientist_factors + ((size_t)sid << 6) + (sub << 3);
    float se[8];
    #pragma unroll
    for (int k = 0; k < 8; ++k) se[k] = __builtin_nontemporal_load(sf + k);

    const float sb = __builtin_nontemporal_load(scientist_bias + sid);
    const float pb = __builtin_nontemporal_load(paper_bias + pid);

    const float base = se[0]*pe0.x + se[1]*pe0.y + se[2]*pe0.z + se[3]*pe0.w
                     + se[4]*pe1.x + se[5]*pe1.y + se[6]*pe1.z + se[7]*pe1.w;

    // gather loop: 4 independent chains; all groups have (near-)equal n.
    float A0 = 0.f, A1 = 0.f, A2 = 0.f, A3 = 0.f;
    float S0 = 0.f, S1 = 0.f, S2 = 0.f, S3 = 0.f;
    int e = start;
    for (; e + 4 <= end; e += 4) {
        const int p0 = flat_papers[e];
        const int p1 = flat_papers[e + 1];
        const int p2 = flat_papers[e + 2];
        const int p3 = flat_papers[e + 3];
        const uint u0 = imp_q4[((size_t)p0 << 3) + sub];
        const uint u1 = imp_q4[((size_t)p1 << 3) + sub];
        const uint u2 = imp_q4[((size_t)p2 << 3) + sub];
        const uint u3 = imp_q4[((size_t)p3 << 3) + sub];
        const float s0 = imp_scale[p0];
        const float s1 = imp_scale[p1];
        const float s2 = imp_scale[p2];
        const float s3 = imp_scale[p3];
        A0 = fmaf(s0, qdot8(u0, pe0, pe1), A0);  S0 += s0;
        A1 = fmaf(s1, qdot8(u1, pe0, pe1), A1);  S1 += s1;
        A2 = fmaf(s2, qdot8(u2, pe0, pe1), A2);  S2 += s2;
        A3 = fmaf(s3, qdot8(u3, pe0, pe1), A3);  S3 += s3;
    }
    for (; e < end; ++e) {
        const int p = flat_papers[e];
        const uint u = imp_q4[((size_t)p << 3) + sub];
        const float s = imp_scale[p];
        A0 = fmaf(s, qdot8(u, pe0, pe1), A0);  S0 += s;
    }
    const float acc = ((A0 + A1) + (A2 + A3))
                    - 7.5f * ((S0 + S1) + (S2 + S3)) * pesum;

    const int n = end - start;
    const float scale = (n > 0) ? rsqrtf((float)n) : 0.0f;
    float v = base + scale * acc;

    // reduce within the 8-lane group (lane bits 0..2)
    v += __shfl_xor(v, 1, 64);
    v += __shfl_xor(v, 2, 64);
    v += __shfl_xor(v, 4, 64);

    if (sub == 0) {
        __builtin_nontemporal_store(v + sb + pb + 3.82f, out + b);
    }
}

// ---------- f32 fallback (ws too small) ----------
__global__ __launch_bounds__(256) void svdpp_main_f32(
    const int*   __restrict__ scientist_ids,
    const int*   __restrict__ paper_ids,
    const int*   __restrict__ flat_papers,
    const int*   __restrict__ row_start,
    const float* __restrict__ scientist_factors,
    const float* __restrict__ paper_factors,
    const float* __restrict__ implicit_factors,
    const float* __restrict__ scientist_bias,
    const float* __restrict__ paper_bias,
    float*       __restrict__ out,
    int B) {
    const int wave = (int)((blockIdx.x * blockDim.x + threadIdx.x) >> 6);
    const int lane = threadIdx.x & 63;
    if (wave >= B) return;
    const int b   = wave;
    const int g   = lane >> 4;
    const int sub = lane & 15;

    const int start = row_start[b];
    const int end   = row_start[b + 1];
    const int n     = end - start;

    float4 accA = make_float4(0.f,0.f,0.f,0.f);
    int i = start;
    for (; i < end; i += 4) {
        const int e = i + g;
        if (e < end) {
            const int p = flat_papers[e];
            const float4 r = *reinterpret_cast<const float4*>(
                implicit_factors + ((size_t)p << 6) + (sub << 2));
            accA.x += r.x; accA.y += r.y; accA.z += r.z; accA.w += r.w;
        }
    }

    const float scale = (n > 0) ? rsqrtf((float)n) : 0.0f;
    const int sid = scientist_ids[b];
    const int pid = paper_ids[b];
    const float4 se = *reinterpret_cast<const float4*>(
        scientist_factors + ((size_t)sid << 6) + (sub << 2));
    const float4 pe = *reinterpret_cast<const float4*>(
        paper_factors + ((size_t)pid << 6) + (sub << 2));

    const float basedot = se.x*pe.x + se.y*pe.y + se.z*pe.z + se.w*pe.w;
    const float tdot    = accA.x*pe.x + accA.y*pe.y + accA.z*pe.z + accA.w*pe.w;
    float v = scale * tdot + ((g == 0) ? basedot : 0.0f);

    #pragma unroll
    for (int off = 1; off < 64; off <<= 1) v += __shfl_xor(v, off, 64);

    if (lane == 0) {
        out[b] = v + scientist_bias[sid] + paper_bias[pid] + 3.82f;
    }
}

extern "C" void kernel_launch(void* const* d_in, const int* in_sizes, int n_in,
                              void* d_out, int out_size, void* d_ws, size_t ws_size,
                              hipStream_t stream) {
    const int* scientist_ids       = (const int*)d_in[0];
    const int* paper_ids           = (const int*)d_in[1];
    const int* flat_papers         = (const int*)d_in[2];
    const int* segment_ids         = (const int*)d_in[3];
    const float* scientist_factors = (const float*)d_in[4];
    const float* paper_factors     = (const float*)d_in[5];
    const float* implicit_factors  = (const float*)d_in[6];
    const float* scientist_bias    = (const float*)d_in[7];
    const float* paper_bias        = (const float*)d_in[8];
    float* out = (float*)d_out;

    const int B      = in_sizes[0];
    const int T      = in_sizes[2];
    const int IMP_N  = in_sizes[6];          // NUM_PAPERS * EMB
    const int NROWS  = IMP_N / EMB;          // NUM_PAPERS

    auto align64 = [](size_t x) { return (x + 63) & ~(size_t)63; };
    size_t off0 = 0;                                   // row_start (B+1 ints)
    size_t off1 = align64(off0 + (size_t)(B + 1) * 4); // imp_q4  (NROWS*32B)
    size_t off2 = align64(off1 + (size_t)NROWS * 32);  // imp_scale (NROWS*4B)
    size_t off3 = align64(off2 + (size_t)NROWS * 4);   // ord (B ints)
    size_t off4 = align64(off3 + (size_t)B * 4);       // hist + cursor
    const size_t need = off4 + 2 * NBINS * 4;

    int*   row_start  = (int*)((char*)d_ws + off0);
    uint*  imp_q4     = (uint*)((char*)d_ws + off1);
    float* imp_scale  = (float*)((char*)d_ws + off2);
    int*   ord        = (int*)((char*)d_ws + off3);
    int*   hist       = (int*)((char*)d_ws + off4);
    int*   bin_cursor = hist + NBINS;

    {
        const int threads = 256;
        const int blocks  = (T + threads - 1) / threads;
        seg_bounds_kernel<<<blocks, threads, 0, stream>>>(segment_ids, row_start, T, B);
    }

    if (ws_size >= need) {
        hipMemsetAsync(hist, 0, NBINS * 4, stream);
        {
            const int threads   = 256;
            const int cvtBlocks = (NROWS + 31) / 32;   // 8 rows per wave
            const int histBlocks = 256;
            cvt_and_hist_kernel<<<cvtBlocks + histBlocks, threads, 0, stream>>>(
                implicit_factors, imp_q4, imp_scale, NROWS, cvtBlocks,
                row_start, hist, B);
        }
        bin_prefix_kernel<<<1, 64, 0, stream>>>(hist, bin_cursor);
        make_order_kernel<<<256, 256, 0, stream>>>(row_start, bin_cursor, ord, B);
        {
            const int threads = 256;                   // 32 rows per block
            const int blocks  = (B + 31) / 32;
            svdpp_main_q4<<<blocks, threads, 0, stream>>>(
                scientist_ids, paper_ids, flat_papers, row_start, ord,
                scientist_factors, paper_factors, imp_q4, imp_scale,
                scientist_bias, paper_bias, out, B);
        }
    } else {
        const int threads = 256;
        const int blocks  = (B + 3) / 4;
        svdpp_main_f32<<<blocks, threads, 0, stream>>>(
            scientist_ids, paper_ids, flat_papers, row_start,
            scientist_factors, paper_factors, implicit_factors,
            scientist_bias, paper_bias, out, B);
    }
}